// Round 7
// baseline (1448.742 us; speedup 1.0000x reference)
//
#include <hip/hip_runtime.h>
#include <hip/hip_bf16.h>
#include <cstdint>

typedef __attribute__((ext_vector_type(8))) short short8;
typedef __attribute__((ext_vector_type(4))) float f32x4;
typedef __attribute__((ext_vector_type(4))) short short4v;

__device__ __forceinline__ float b2f(short s) {
    unsigned u = ((unsigned)(unsigned short)s) << 16;
    return __builtin_bit_cast(float, u);
}
__device__ __forceinline__ short f2b(float f) {
    unsigned u = __builtin_bit_cast(unsigned, f);
    u += 0x7fff + ((u >> 16) & 1);   // RNE
    return (short)(u >> 16);
}

__device__ __forceinline__ float gelu_t(float x) {
    float u = 0.7978845608028654f * (x + 0.044715f * x * x * x);
    float e = __expf(2.0f * u);
    float t = 1.0f - __fdividef(2.0f, e + 1.0f);
    return 0.5f * x * (1.0f + t);
}

__device__ __forceinline__ void async16(const void* g, void* l) {
    __builtin_amdgcn_global_load_lds(
        (const __attribute__((address_space(1))) unsigned int*)g,
        (__attribute__((address_space(3))) unsigned int*)l, 16, 0, 0);
}

// Ash layout: [128 rows][512 cols] bf16, chunk-swizzled: 16B-chunk c of row r
// stored at chunk (c ^ (r&15)).  Short-index helper (chunk-aligned access):
__device__ __forceinline__ int ashC(int r, int c) {            // chunk index c in 0..63
    return r * 512 + (((c) ^ (r & 15)) << 3);
}

// =====================================================================
// Mega-kernel: block = 128 rows x one view k (blockIdx.z).
//   k==0 : encoder(x);  k>=1 : transform_k (3 layers) then encoder (3)
// Activations resident in LDS Ash[128][512] (swizzled). Weights stream
// global->LDS (Wbuf, BK=32) in the proven 2-phase ordering. Ends with
// fused LN + L2-normalize + coalesced z write.  LDS = 160 KiB exactly.
// =====================================================================
__global__ __launch_bounds__(512, 2)
void mega_kernel(const short* __restrict__ xb,     // [CH,512] bf16
                 const short* __restrict__ wt,     // 36 mats [512][512] n-major
                 const float* __restrict__ tb1, const float* __restrict__ tb2,
                 const float* __restrict__ tb3,
                 const float* __restrict__ eb1, const float* __restrict__ eb2,
                 const float* __restrict__ eb3,
                 const float* __restrict__ lngm, const float* __restrict__ lnbt,
                 short* __restrict__ zst,          // [12,CH,512] bf16
                 int CH) {
    __shared__ alignas(16) short Ash[128 * 512];   // 131072 B
    __shared__ alignas(16) short Wbuf[512 * 32];   //  32768 B

    const int tid  = threadIdx.x;
    const int lane = tid & 63;
    const int w    = tid >> 6;           // 0..7
    const int wr   = w >> 2, wc = w & 3; // 2x4 wave grid: 64 rows x 128 cols
    const int kview = blockIdx.z;
    const long row0 = (long)blockIdx.x * 128;
    const long WM   = 512L * 512L;
    const int  NS   = (kview == 0) ? 48 : 96;   // 16 K-steps of 32 per layer

    // ---- x tile -> Ash (each wave writes one full row per iter) ----
    for (int it = 0; it < 16; ++it) {
        const int r = it * 8 + w;                  // wave-uniform row
        short8 v = *(const short8*)&xb[(row0 + r) * 512 + lane * 8];
        *(short8*)&Ash[ashC(r, lane)] = v;
    }

    f32x4 acc[4][8] = {};
    const int lr  = lane & 15, hi = lane >> 4;
    const int swz = (hi ^ (lr >> 2)) * 8;          // W read swizzle (shorts)
    const int srow = lane >> 2;                    // stage: row in 16-group
    const int gch  = (lane & 3) ^ (lane >> 4);     // stage: pre-swz global chunk

    for (int s = 0; s < NS; ++s) {
        const int l  = s >> 4;
        const int le = (kview == 0) ? l + 3 : l;
        const long widx = (le == 0) ? (long)(kview - 1)
                        : (le == 1) ? (long)(11 + kview - 1)
                        : (le == 2) ? (long)(22 + kview - 1)
                        : (long)(33 + (le - 3));

        __syncthreads();   // prev compute's Wbuf reads done; Ash epilogue visible
        {
            const short* Ws = wt + widx * WM + (long)(s & 15) * 32;
#pragma unroll
            for (int i = 0; i < 4; ++i) {
                const int r0 = w * 64 + i * 16;    // wave-uniform LDS base
                async16(Ws + (long)(r0 + srow) * 512 + gch * 8, Wbuf + r0 * 32);
            }
        }
        __syncthreads();   // W landed (barrier drains vmcnt)

        short8 a[4];
#pragma unroll
        for (int m = 0; m < 4; ++m) {
            const int row = wr * 64 + m * 16 + lr;
            a[m] = *(const short8*)&Ash[ashC(row, (s & 15) * 4 + hi)];
        }
#pragma unroll
        for (int n = 0; n < 8; ++n) {
            const int rown = wc * 128 + n * 16 + lr;
            short8 bf = *(const short8*)&Wbuf[rown * 32 + swz];
#pragma unroll
            for (int m = 0; m < 4; ++m)
                acc[m][n] = __builtin_amdgcn_mfma_f32_16x16x32_bf16(a[m], bf, acc[m][n], 0, 0, 0);
        }

        if ((s & 15) == 15) {
            __syncthreads();     // all waves' layer-l Ash reads done
            const float* bp = (le == 0) ? tb1 + (long)(kview - 1) * 512
                            : (le == 1) ? tb2 + (long)(kview - 1) * 512
                            : (le == 2) ? tb3 + (long)(kview - 1) * 512
                            : (le == 3) ? eb1 : (le == 4) ? eb2 : eb3;
            const bool g = (le == 0) | (le == 1) | (le == 3) | (le == 4);
#pragma unroll
            for (int n = 0; n < 8; ++n) {
                const int col = wc * 128 + n * 16 + lr;
                const float bv = bp[col];
#pragma unroll
                for (int m = 0; m < 4; ++m) {
#pragma unroll
                    for (int i = 0; i < 4; ++i) {
                        const int row = wr * 64 + m * 16 + hi * 4 + i;
                        float v = acc[m][n][i] + bv;
                        if (g) v = gelu_t(v);
                        Ash[ashC(row, col >> 3) + (col & 7)] = f2b(v);
                    }
                    acc[m][n] = (f32x4){0.f, 0.f, 0.f, 0.f};
                }
            }
            // visibility to next layer: loop-top barrier + stage barrier
        }
    }

    __syncthreads();   // final epilogue visible

    // ---- fused LN + L2-normalize + z write: one wave per row ----
    for (int it = 0; it < 16; ++it) {
        const int row = it * 8 + w;
        short8 t = *(const short8*)&Ash[ashC(row, lane)];
        float v[8];
        float sum = 0.f, ss = 0.f;
#pragma unroll
        for (int j = 0; j < 8; ++j) { v[j] = b2f(t[j]); sum += v[j]; ss += v[j] * v[j]; }
#pragma unroll
        for (int o = 1; o < 64; o <<= 1) { sum += __shfl_xor(sum, o, 64); ss += __shfl_xor(ss, o, 64); }
        const float mu = sum * (1.f / 512.f);
        const float var = ss * (1.f / 512.f) - mu * mu;
        const float rs = rsqrtf(var + 1e-5f);
        float y[8]; float nsq = 0.f;
#pragma unroll
        for (int j = 0; j < 8; ++j) {
            const int col = lane * 8 + j;
            y[j] = (v[j] - mu) * rs * lngm[col] + lnbt[col];
            nsq += y[j] * y[j];
        }
#pragma unroll
        for (int o = 1; o < 64; o <<= 1) nsq += __shfl_xor(nsq, o, 64);
        const float inv = 1.f / fmaxf(sqrtf(nsq), 1e-8f);
        short8 o8;
#pragma unroll
        for (int j = 0; j < 8; ++j) o8[j] = f2b(y[j] * inv);
        *(short8*)&zst[((long)kview * CH + row0 + row) * 512 + lane * 8] = o8;
    }
}

// ---- transpose+convert: dst[n][k] = bf16(src[k][n]), one 512x512 per blockIdx.z ----
__global__ __launch_bounds__(256)
void transpose_conv(const float* __restrict__ src, short* __restrict__ dst) {
    __shared__ float t[32][33];
    const long moff = (long)blockIdx.z * 512 * 512;
    const float* s = src + moff;
    short* d = dst + moff;
    const int tx = threadIdx.x & 31, ty = threadIdx.x >> 5;
    const int bi = blockIdx.x, bj = blockIdx.y;
#pragma unroll
    for (int j = 0; j < 4; ++j)
        t[ty + j * 8][tx] = s[(long)(bi * 32 + ty + j * 8) * 512 + bj * 32 + tx];
    __syncthreads();
#pragma unroll
    for (int j = 0; j < 4; ++j)
        d[(long)(bj * 32 + ty + j * 8) * 512 + bi * 32 + tx] = f2b(t[tx][ty + j * 8]);
}

// ---- f32 -> bf16 elementwise ----
__global__ __launch_bounds__(256)
void conv_f32_bf16(const float* __restrict__ src, short* __restrict__ dst, long n) {
    long i = ((long)blockIdx.x * 256 + threadIdx.x) * 4;
    if (i >= n) return;
    float4 f = *(const float4*)&src[i];
    short4v o;
    o[0] = f2b(f.x); o[1] = f2b(f.y); o[2] = f2b(f.z); o[3] = f2b(f.w);
    *(short4v*)&dst[i] = o;
}

// ---- loss: 4 waves/block, one b per wave; 12x12 Gram + per-k logsumexp ----
__global__ __launch_bounds__(256)
void loss_kernel(const short* __restrict__ Z, float* __restrict__ out, int CH) {
    const int wid = threadIdx.x >> 6, lane = threadIdx.x & 63;
    const long b = (long)blockIdx.x * 4 + wid;
    __shared__ float G[4][12][12];
    float v[12][8];
#pragma unroll
    for (int sIdx = 0; sIdx < 12; ++sIdx) {
        short8 t = *(const short8*)&Z[((long)sIdx * CH + b) * 512 + lane * 8];
#pragma unroll
        for (int j = 0; j < 8; ++j) v[sIdx][j] = b2f(t[j]);
    }
#pragma unroll
    for (int i = 0; i < 12; ++i) {
#pragma unroll
        for (int j = i + 1; j < 12; ++j) {
            float p = 0.f;
#pragma unroll
            for (int t = 0; t < 8; ++t) p += v[i][t] * v[j][t];
#pragma unroll
            for (int o = 1; o < 64; o <<= 1) p += __shfl_xor(p, o, 64);
            if (lane == 0) { G[wid][i][j] = p; G[wid][j][i] = p; }
        }
    }
    __syncthreads();
    float contrib = 0.f;
    if (lane >= 1 && lane <= 11) {
        const int k = lane;
        const float pos = G[wid][0][k];
        float mx = pos;
        for (int l = 1; l <= 11; ++l) if (l != k) mx = fmaxf(mx, G[wid][l][k]);
        float sum = expf(pos - mx);
        for (int l = 1; l <= 11; ++l) if (l != k) sum += expf(G[wid][l][k] - mx);
        contrib = pos - (mx + logf(sum));
    }
#pragma unroll
    for (int o = 1; o < 64; o <<= 1) contrib += __shfl_xor(contrib, o, 64);
    if (lane == 0) out[b] = -contrib;
}

// ---------------- host ----------------
extern "C" void kernel_launch(void* const* d_in, const int* in_sizes, int n_in,
                              void* d_out, int out_size, void* d_ws, size_t ws_size,
                              hipStream_t stream) {
    const float* x    = (const float*)d_in[0];
    const float* tW1  = (const float*)d_in[1];
    const float* tb1  = (const float*)d_in[2];
    const float* tW2  = (const float*)d_in[3];
    const float* tb2  = (const float*)d_in[4];
    const float* tW3  = (const float*)d_in[5];
    const float* tb3  = (const float*)d_in[6];
    const float* eW1  = (const float*)d_in[7];
    const float* eb1  = (const float*)d_in[8];
    const float* eW2  = (const float*)d_in[9];
    const float* eb2  = (const float*)d_in[10];
    const float* eW3  = (const float*)d_in[11];
    const float* eb3  = (const float*)d_in[12];
    const float* ln_g = (const float*)d_in[13];
    const float* ln_b = (const float*)d_in[14];

    const int  B    = in_sizes[0] / 512;   // 16384
    const long WMAT = 512L * 512L;

    // ---- adaptive chunking: weights + xb + 12 z slabs (bf16) ----
    int  c  = 1;
    long CH = B;
    for (;;) {
        CH = (long)B / c;
        size_t need = (size_t)36 * WMAT * 2 + (size_t)13 * CH * 512 * 2 + 4096;
        if (need <= ws_size || CH <= 128) break;
        c <<= 1;
    }

    short* wt  = (short*)d_ws;             // 36 transposed bf16 weight mats
    short* xb  = wt + 36L * WMAT;          // [CH,512] bf16 chunk of x
    short* zst = xb + CH * 512;            // [12,CH,512] bf16 z-store

    // --- weight transpose+convert (once) ---
    {
        dim3 tgK(16, 16, 11), tg1(16, 16, 1);
        transpose_conv<<<tgK, 256, 0, stream>>>(tW1, wt + 0L * WMAT);
        transpose_conv<<<tgK, 256, 0, stream>>>(tW2, wt + 11L * WMAT);
        transpose_conv<<<tgK, 256, 0, stream>>>(tW3, wt + 22L * WMAT);
        transpose_conv<<<tg1, 256, 0, stream>>>(eW1, wt + 33L * WMAT);
        transpose_conv<<<tg1, 256, 0, stream>>>(eW2, wt + 34L * WMAT);
        transpose_conv<<<tg1, 256, 0, stream>>>(eW3, wt + 35L * WMAT);
    }

    const long SC = CH * 512;
    const dim3 gM((unsigned)(CH / 128), 1, 12);

    for (int ch = 0; ch < c; ++ch) {
        conv_f32_bf16<<<(unsigned)((SC / 4 + 255) / 256), 256, 0, stream>>>(
            x + (long)ch * SC, xb, SC);

        mega_kernel<<<gM, 512, 0, stream>>>(xb, wt, tb1, tb2, tb3, eb1, eb2, eb3,
                                            ln_g, ln_b, zst, (int)CH);

        loss_kernel<<<(unsigned)(CH / 4), 256, 0, stream>>>(
            zst, (float*)d_out + (long)ch * CH, (int)CH);
    }
}